// Round 5
// baseline (169.234 us; speedup 1.0000x reference)
//
#include <hip/hip_runtime.h>

namespace {

constexpr int kH  = 1024;
constexpr int kW  = 1024;
constexpr int kHW = kH * kW;
constexpr int kSH = 68;           // int(1023/16)+1+2*2
constexpr int kSW = 68;
constexpr int kD  = 8;            // max depth; features uniform [0,1) -> depth <= 8
constexpr int kT3 = kSH * kSW * kD * kD * kD;   // 2,367,488 cells per channel
// fixed strides (floats) inside one channel grid [68][68][8][8][8]
constexpr int kSG = 8;
constexpr int kSR = 64;
constexpr int kSX = 512;
constexpr int kSY = 512 * 68;     // 34816
constexpr int kLines = 3 * kSH * kSW * kD * kD; // 887,808 b-lines of 8 cells

// ---- header layout in d_ws (uint words) ----
// [0..2] min bits per channel   [3..5] max bits per channel
// [8] dr [9] dg [10] db

__global__ void init_hdr_kernel(unsigned* hdr) {
    int t = threadIdx.x;
    if (t < 3) hdr[t] = 0x7f800000u;      // +inf (values >= 0, bit order == value order)
    else if (t < 6) hdr[t] = 0u;
}

__global__ void minmax_kernel(const float* __restrict__ feat, unsigned* hdr) {
    float mn[3] = {1e30f, 1e30f, 1e30f};
    float mx[3] = {-1e30f, -1e30f, -1e30f};
    int tid = blockIdx.x * blockDim.x + threadIdx.x;
    int stride = gridDim.x * blockDim.x;
    for (int p = tid; p < kHW; p += stride) {
        #pragma unroll
        for (int c = 0; c < 3; ++c) {
            float v = feat[p * 3 + c];
            mn[c] = fminf(mn[c], v);
            mx[c] = fmaxf(mx[c], v);
        }
    }
    #pragma unroll
    for (int off = 32; off > 0; off >>= 1) {
        #pragma unroll
        for (int c = 0; c < 3; ++c) {
            mn[c] = fminf(mn[c], __shfl_down(mn[c], off, 64));
            mx[c] = fmaxf(mx[c], __shfl_down(mx[c], off, 64));
        }
    }
    __shared__ float smn[4][3], smx[4][3];
    int wave = threadIdx.x >> 6;
    if ((threadIdx.x & 63) == 0) {
        #pragma unroll
        for (int c = 0; c < 3; ++c) { smn[wave][c] = mn[c]; smx[wave][c] = mx[c]; }
    }
    __syncthreads();
    if (threadIdx.x == 0) {
        #pragma unroll
        for (int c = 0; c < 3; ++c) {
            float bmn = fminf(fminf(smn[0][c], smn[1][c]), fminf(smn[2][c], smn[3][c]));
            float bmx = fmaxf(fmaxf(smx[0][c], smx[1][c]), fmaxf(smx[2][c], smx[3][c]));
            atomicMin(&hdr[c],     __float_as_uint(bmn));
            atomicMax(&hdr[3 + c], __float_as_uint(bmx));
        }
    }
}

__global__ void params_kernel(unsigned* hdr) {
    if (threadIdx.x == 0 && blockIdx.x == 0) {
        int* ip = (int*)(hdr + 8);
        for (int c = 0; c < 3; ++c) {
            float mnf = __uint_as_float(hdr[c]);
            float mxf = __uint_as_float(hdr[3 + c]);
            float delta = mxf - mnf;                        // fp32 sub, like numpy
            int depth = (int)((double)delta / 0.25) + 1 + 4;
            if (depth > kD) depth = kD;
            if (depth < 1) depth = 1;
            ip[c] = depth;
        }
    }
}

// Privatized splat over the FULL 68x68 cell grid: boundary cells get zeros;
// each interior cell is fed by exactly one pixel band -> LDS histogram,
// coalesced stores, zero global atomics.
__global__ void splat_kernel(const float* __restrict__ feat,
                             const float* __restrict__ inp,
                             const unsigned* __restrict__ hdr,
                             float* __restrict__ grid) {
    int bx = blockIdx.x, by = blockIdx.y;          // 68 x 68 cells
    long base = ((long)(by * kSW + bx)) << 9;
    bool boundary = (by < 2) || (by > 66) || (bx < 2) || (bx > 66);
    if (boundary) {
        float4 z = make_float4(0.f, 0.f, 0.f, 0.f);
        float4* d0 = (float4*)(grid + base);
        float4* d1 = (float4*)(grid + kT3 + base);
        float4* d2 = (float4*)(grid + 2 * kT3 + base);
        for (int i = threadIdx.x; i < 128; i += 256) { d0[i] = z; d1[i] = z; d2[i] = z; }
        return;
    }
    int iy = by - 2, ix = bx - 2;                  // band index 0..64
    int y0 = (iy == 0) ? 0 : 16 * iy - 8;
    int x0 = (ix == 0) ? 0 : 16 * ix - 8;
    int h = (iy == 0 || iy == 64) ? 8 : 16;
    int w = (ix == 0 || ix == 64) ? 8 : 16;

    __shared__ float acc[3 * 512];
    for (int i = threadIdx.x; i < 3 * 512; i += 256) acc[i] = 0.0f;
    __syncthreads();

    int t = threadIdx.x;
    int n = w * h;
    if (t < n) {
        int lx = t & (w - 1);
        int ly = (w == 16) ? (t >> 4) : (t >> 3);
        int y = y0 + ly, x = x0 + lx;
        int p = (y << 10) + x;
        float v0 = feat[p * 3 + 0] - __uint_as_float(hdr[0]);
        float v1 = feat[p * 3 + 1] - __uint_as_float(hdr[1]);
        float v2 = feat[p * 3 + 2] - __uint_as_float(hdr[2]);
        int sr = (int)(v0 * 4.0f + 0.5f) + 2;   // /0.25 == *4 exact
        int sg = (int)(v1 * 4.0f + 0.5f) + 2;
        int sb = (int)(v2 * 4.0f + 0.5f) + 2;
        int ci = (sr << 6) + (sg << 3) + sb;
        atomicAdd(&acc[ci],            inp[p * 3 + 0]);
        atomicAdd(&acc[512 + ci],      inp[p * 3 + 1]);
        atomicAdd(&acc[1024 + ci],     inp[p * 3 + 2]);
    }
    __syncthreads();

    for (int i = threadIdx.x; i < 512; i += 256) {
        grid[base + i]            = acc[i];
        grid[kT3 + base + i]      = acc[512 + i];
        grid[2 * kT3 + base + i]  = acc[1024 + i];
    }
}

// BOTH _convn outer-iterations fused into one pass (src = splat, dst = final).
// Per-cell final value = blur along its highest-priority interior axis
// (b > g > r > x > y), where iteration 2 reads iteration-1 values:
//   b interior:  out2[b] = stencil_b(o1) — o1 entirely within this line.
//   b end, fs!=0: out2[b] = (out1(c-fs) + out1(c+fs) + 2*o1[b])/4, where
//                 out1 at a neighbor line is that line's own fallback blur
//                 of the splat (3 cached scalar loads each).
//   fs==0 (all-axis-boundary line): ends retain the original splat (iter-2
//                 data starts as the splat); o1 ends are 0 (iter-1 zero data).
// fs (fallback stride) is b-independent, i.e. uniform per line.
__global__ void blur2_kernel(float* __restrict__ dst,
                             const float* __restrict__ src,
                             const unsigned* __restrict__ hdr) {
    int line = blockIdx.x * blockDim.x + threadIdx.x;
    if (line >= kLines) return;
    const int* ip = (const int*)(hdr + 8);
    int dr = ip[0], dg = ip[1], db = ip[2];

    int g = line & 7;
    int r = (line >> 3) & 7;
    int rest = line >> 6;           // ch*68*68 + y*68 + x
    int x = rest % 68;
    int y = (rest / 68) % 68;

    long base = (long)line * 8;
    const float4* s4 = (const float4*)(src + base);
    float4 lo = s4[0], hi = s4[1];
    float v[8] = {lo.x, lo.y, lo.z, lo.w, hi.x, hi.y, hi.z, hi.w};

    auto fsOf = [&](int gg, int rr, int xx, int yy) -> int {
        if (gg >= 1 && gg <= dg - 2) return kSG;
        if (rr >= 1 && rr <= dr - 2) return kSR;
        if (xx >= 1 && xx <= kSW - 2) return kSX;
        if (yy >= 1 && yy <= kSH - 2) return kSY;
        return 0;
    };
    int fs = fsOf(g, r, x, y);

    // iter-1 values for this line
    float o1[8];
    #pragma unroll
    for (int b = 0; b < 8; ++b) {
        if (b >= 1 && b <= db - 2)
            o1[b] = ((v[b - 1] + v[b + 1]) + 2.0f * v[b]) * 0.25f;
        else if (fs != 0)
            o1[b] = ((src[base + b - fs] + src[base + b + fs]) + 2.0f * v[b]) * 0.25f;
        else
            o1[b] = 0.0f;
    }

    // fallback strides of the two ±fs neighbor lines (needed for end cells)
    int fsm = 0, fsp = 0;
    if (fs != 0) {
        int gm = g, rm = r, xm = x, ym = y, gp = g, rp = r, xp = x, yp = y;
        if (fs == kSG)      { gm--; gp++; }
        else if (fs == kSR) { rm--; rp++; }
        else if (fs == kSX) { xm--; xp++; }
        else                { ym--; yp++; }
        fsm = fsOf(gm, rm, xm, ym);
        fsp = fsOf(gp, rp, xp, yp);
    }

    float out[8];
    #pragma unroll
    for (int b = 0; b < 8; ++b) {
        if (b >= 1 && b <= db - 2) {
            out[b] = ((o1[b - 1] + o1[b + 1]) + 2.0f * o1[b]) * 0.25f;
        } else if (b < db) {
            if (fs != 0) {
                long nbm = base - fs + b, nbp = base + fs + b;
                float Xm = (fsm != 0)
                    ? ((src[nbm - fsm] + src[nbm + fsm]) + 2.0f * src[nbm]) * 0.25f
                    : 0.0f;
                float Xp = (fsp != 0)
                    ? ((src[nbp - fsp] + src[nbp + fsp]) + 2.0f * src[nbp]) * 0.25f
                    : 0.0f;
                out[b] = ((Xm + Xp) + 2.0f * o1[b]) * 0.25f;
            } else {
                out[b] = v[b];      // retain original splat
            }
        } else {
            out[b] = 0.0f;          // inactive depth slot
        }
    }
    float4* d4 = (float4*)(dst + base);
    d4[0] = make_float4(out[0], out[1], out[2], out[3]);
    d4[1] = make_float4(out[4], out[5], out[6], out[7]);
}

// LDS-staged slice: one workgroup per 32x32 pixel tile (1024 threads). The
// tile's spatial footprint is 3x3 cells -> stage 9 cells x 512 colors x 3 ch
// (54 KB) with coalesced float4 loads (2.25x staging redundancy vs 4x for
// 16x16 tiles), then gather all penta-linear corners from LDS.
__global__ __launch_bounds__(1024) void slice_kernel(const float* __restrict__ feat,
                                                     const unsigned* __restrict__ hdr,
                                                     const float* __restrict__ grid,
                                                     float* __restrict__ out) {
    __shared__ float sg[3 * 9 * 512];   // [ch][cell(3x3)][512]
    int tx = blockIdx.x, ty = blockIdx.y;   // 32 x 32 tiles

    {
        const float4* g4 = (const float4*)grid;
        float4* s4 = (float4*)sg;
        for (int i = threadIdx.x; i < 3 * 9 * 128; i += 1024) {
            int ch = i / 1152;          // 9*128
            int rem = i - ch * 1152;
            int cell = rem >> 7;        // 0..8
            int ci4 = rem & 127;
            int cy = 2 * ty + 2 + cell / 3;
            int cx = 2 * tx + 2 + cell % 3;
            long cbase4 = ((long)(cy * kSW + cx)) << 7;   // 128 float4 per cell
            s4[i] = g4[(long)ch * (kT3 / 4) + cbase4 + ci4];
        }
    }
    __syncthreads();

    const int* ip = (const int*)(hdr + 8);
    int d3[3] = {ip[0], ip[1], ip[2]};
    int lx = threadIdx.x & 31, ly = threadIdx.x >> 5;
    int y = (ty << 5) + ly, x = (tx << 5) + lx;
    int p = (y << 10) + x;

    float ya = (float)(ly & 15) * 0.0625f;   // exact fractional part of y/16
    float xa = (float)(lx & 15) * 0.0625f;
    int cyl = ly >> 4, cxl = lx >> 4;        // 0..1 local cell origin

    int li[3], ri[3];
    float al[3];
    #pragma unroll
    for (int c = 0; c < 3; ++c) {
        float v0 = feat[p * 3 + c] - __uint_as_float(hdr[c]);
        float sv = v0 * 4.0f + 2.0f;
        int l = (int)sv;
        int dm = d3[c] - 1;
        l = l < 0 ? 0 : (l > dm ? dm : l);
        int rr = l + 1 > dm ? dm : l + 1;
        li[c] = l; ri[c] = rr; al[c] = sv - (float)l;
    }

    int sci[4]; float spw[4];
    {
        float wy[2] = {1.0f - ya, ya};
        float wx[2] = {1.0f - xa, xa};
        #pragma unroll
        for (int dy = 0; dy < 2; ++dy)
        #pragma unroll
        for (int dx = 0; dx < 2; ++dx) {
            int k = dy * 2 + dx;
            sci[k] = ((cyl + dy) * 3 + (cxl + dx)) << 9;
            spw[k] = wy[dy] * wx[dx];
        }
    }
    int cpi[8]; float cpw[8];
    {
        int rs[2] = {li[0], ri[0]}; float wrr[2] = {1.0f - al[0], al[0]};
        int gs[2] = {li[1], ri[1]}; float wgg[2] = {1.0f - al[1], al[1]};
        int bs[2] = {li[2], ri[2]}; float wbb[2] = {1.0f - al[2], al[2]};
        #pragma unroll
        for (int cr = 0; cr < 2; ++cr)
        #pragma unroll
        for (int cg = 0; cg < 2; ++cg)
        #pragma unroll
        for (int cb = 0; cb < 2; ++cb) {
            int k = (cr * 2 + cg) * 2 + cb;
            cpi[k] = (rs[cr] << 6) + (gs[cg] << 3) + bs[cb];
            cpw[k] = (wrr[cr] * wgg[cg]) * wbb[cb];
        }
    }

    float acc0 = 0.0f, acc1 = 0.0f, acc2 = 0.0f;
    #pragma unroll
    for (int k = 0; k < 4; ++k) {
        #pragma unroll
        for (int j = 0; j < 8; ++j) {
            int si = sci[k] + cpi[j];
            float w = spw[k] * cpw[j];
            acc0 += w * sg[si];
            acc1 += w * sg[4608 + si];
            acc2 += w * sg[9216 + si];
        }
    }
    out[p * 3 + 0] = acc0;
    out[p * 3 + 1] = acc1;
    out[p * 3 + 2] = acc2;
}

}  // namespace

extern "C" void kernel_launch(void* const* d_in, const int* in_sizes, int n_in,
                              void* d_out, int out_size, void* d_ws, size_t ws_size,
                              hipStream_t stream) {
    const float* feat = (const float*)d_in[0];
    const float* inp  = (const float*)d_in[1];
    float* out = (float*)d_out;

    unsigned* hdr = (unsigned*)d_ws;
    float* gridA = (float*)((char*)d_ws + 256);        // splat
    float* gridB = gridA + 3 * (size_t)kT3;            // fused blur output

    init_hdr_kernel<<<1, 64, 0, stream>>>(hdr);
    minmax_kernel<<<256, 256, 0, stream>>>(feat, hdr);
    params_kernel<<<1, 1, 0, stream>>>(hdr);

    splat_kernel<<<dim3(68, 68), 256, 0, stream>>>(feat, inp, hdr, gridA);

    int blurBlocks = (kLines + 255) / 256;
    blur2_kernel<<<blurBlocks, 256, 0, stream>>>(gridB, gridA, hdr);

    slice_kernel<<<dim3(32, 32), 1024, 0, stream>>>(feat, hdr, gridB, out);
}

// Round 6
// 144.024 us; speedup vs baseline: 1.1750x; 1.1750x over previous
//
#include <hip/hip_runtime.h>

namespace {

constexpr int kH  = 1024;
constexpr int kW  = 1024;
constexpr int kHW = kH * kW;
constexpr int kSH = 68;           // int(1023/16)+1+2*2
constexpr int kSW = 68;
constexpr int kD  = 8;            // max depth; features uniform [0,1) -> depth <= 8
constexpr int kT3 = kSH * kSW * kD * kD * kD;   // 2,367,488 cells per channel

// ---- ws layout ----
// bytes [0..256):    hdrF floats [0..2]=channel mins; ints at +8 words: dr,dg,db
// bytes [1024..7168): minmax partials, 256 blocks x 6 floats
// bytes [8192..):    gridA (splat), then gridB (blurred)

__global__ void minmax_kernel(const float* __restrict__ feat, float* __restrict__ part) {
    float mn[3] = {1e30f, 1e30f, 1e30f};
    float mx[3] = {-1e30f, -1e30f, -1e30f};
    int tid = blockIdx.x * blockDim.x + threadIdx.x;
    int stride = gridDim.x * blockDim.x;
    for (int p = tid; p < kHW; p += stride) {
        #pragma unroll
        for (int c = 0; c < 3; ++c) {
            float v = feat[p * 3 + c];
            mn[c] = fminf(mn[c], v);
            mx[c] = fmaxf(mx[c], v);
        }
    }
    #pragma unroll
    for (int off = 32; off > 0; off >>= 1) {
        #pragma unroll
        for (int c = 0; c < 3; ++c) {
            mn[c] = fminf(mn[c], __shfl_down(mn[c], off, 64));
            mx[c] = fmaxf(mx[c], __shfl_down(mx[c], off, 64));
        }
    }
    __shared__ float smn[4][3], smx[4][3];
    int wave = threadIdx.x >> 6;
    if ((threadIdx.x & 63) == 0) {
        #pragma unroll
        for (int c = 0; c < 3; ++c) { smn[wave][c] = mn[c]; smx[wave][c] = mx[c]; }
    }
    __syncthreads();
    if (threadIdx.x == 0) {
        #pragma unroll
        for (int c = 0; c < 3; ++c) {
            part[blockIdx.x * 6 + c]     = fminf(fminf(smn[0][c], smn[1][c]), fminf(smn[2][c], smn[3][c]));
            part[blockIdx.x * 6 + 3 + c] = fmaxf(fmaxf(smx[0][c], smx[1][c]), fmaxf(smx[2][c], smx[3][c]));
        }
    }
}

__global__ void params_kernel(const float* __restrict__ part, float* __restrict__ hdrF) {
    int t = threadIdx.x;   // 256 threads, one per partial
    float mn[3], mx[3];
    #pragma unroll
    for (int c = 0; c < 3; ++c) { mn[c] = part[t * 6 + c]; mx[c] = part[t * 6 + 3 + c]; }
    #pragma unroll
    for (int off = 32; off > 0; off >>= 1) {
        #pragma unroll
        for (int c = 0; c < 3; ++c) {
            mn[c] = fminf(mn[c], __shfl_down(mn[c], off, 64));
            mx[c] = fmaxf(mx[c], __shfl_down(mx[c], off, 64));
        }
    }
    __shared__ float smn[4][3], smx[4][3];
    int wave = t >> 6;
    if ((t & 63) == 0) {
        #pragma unroll
        for (int c = 0; c < 3; ++c) { smn[wave][c] = mn[c]; smx[wave][c] = mx[c]; }
    }
    __syncthreads();
    if (t == 0) {
        int* ip = (int*)(hdrF + 8);
        #pragma unroll
        for (int c = 0; c < 3; ++c) {
            float bmn = fminf(fminf(smn[0][c], smn[1][c]), fminf(smn[2][c], smn[3][c]));
            float bmx = fmaxf(fmaxf(smx[0][c], smx[1][c]), fmaxf(smx[2][c], smx[3][c]));
            float delta = bmx - bmn;                        // fp32 sub, like numpy
            int depth = (int)((double)delta / 0.25) + 1 + 4;
            if (depth > kD) depth = kD;
            if (depth < 1) depth = 1;
            hdrF[c] = bmn;
            ip[c] = depth;
        }
    }
}

// Privatized splat: one block per INTERIOR cell [2,66]^2 (boundary cells are
// never read — blur2 treats out-of-range cells as zero). LDS histogram,
// coalesced stores, zero global atomics.
__global__ void splat_kernel(const float* __restrict__ feat,
                             const float* __restrict__ inp,
                             const float* __restrict__ hdrF,
                             float* __restrict__ grid) {
    int ix = blockIdx.x, iy = blockIdx.y;          // band index 0..64
    int y0 = (iy == 0) ? 0 : 16 * iy - 8;
    int x0 = (ix == 0) ? 0 : 16 * ix - 8;
    int h = (iy == 0 || iy == 64) ? 8 : 16;
    int w = (ix == 0 || ix == 64) ? 8 : 16;

    __shared__ float acc[3 * 512];
    for (int i = threadIdx.x; i < 3 * 512; i += 256) acc[i] = 0.0f;
    __syncthreads();

    int t = threadIdx.x;
    int n = w * h;
    if (t < n) {
        int lx = t & (w - 1);
        int ly = (w == 16) ? (t >> 4) : (t >> 3);
        int y = y0 + ly, x = x0 + lx;
        int p = (y << 10) + x;
        float v0 = feat[p * 3 + 0] - hdrF[0];
        float v1 = feat[p * 3 + 1] - hdrF[1];
        float v2 = feat[p * 3 + 2] - hdrF[2];
        int sr = (int)(v0 * 4.0f + 0.5f) + 2;   // /0.25 == *4 exact
        int sg = (int)(v1 * 4.0f + 0.5f) + 2;
        int sb = (int)(v2 * 4.0f + 0.5f) + 2;
        int ci = (sr << 6) + (sg << 3) + sb;
        atomicAdd(&acc[ci],            inp[p * 3 + 0]);
        atomicAdd(&acc[512 + ci],      inp[p * 3 + 1]);
        atomicAdd(&acc[1024 + ci],     inp[p * 3 + 2]);
    }
    __syncthreads();

    long base = ((long)((iy + 2) * kSW + (ix + 2))) << 9;
    for (int i = threadIdx.x; i < 512; i += 256) {
        grid[base + i]            = acc[i];
        grid[kT3 + base + i]      = acc[512 + i];
        grid[2 * kT3 + base + i]  = acc[1024 + i];
    }
}

// Both _convn outer-iterations, LDS-resident per spatial cell.
// One 192-thread block per interior cell (cy,cx in [2,66]); thread = (ch,line).
// Splat staged transposed Sv[ch][b][rg] -> all stencil reads are stride-1
// (conflict-free). Fallback-axis chain per line is g -> r -> x (y and "none"
// are unreachable for interior cells since x in [1,66] always holds); cells
// outside [2,66]^2 have zero splat and are short-circuited without loading.
__global__ __launch_bounds__(192) void blur2_kernel(float* __restrict__ dst,
                                                    const float* __restrict__ src,
                                                    const float* __restrict__ hdrF) {
    int cx = blockIdx.x + 2, cy = blockIdx.y + 2;   // [2,66]
    const int* ip = (const int*)(hdrF + 8);
    int dr = ip[0], dg = ip[1], db = ip[2];

    __shared__ float Sv[3 * 512];   // [ch][b][rg] transposed
    long cbase = ((long)(cy * kSW + cx)) << 9;

    {
        const float4* g4 = (const float4*)src;
        for (int i = threadIdx.x; i < 384; i += 192) {
            int ch = i >> 7, i4 = i & 127;
            float4 q = g4[(long)ch * (kT3 / 4) + (cbase >> 2) + i4];
            int rg = i4 >> 1;
            int b0 = (i4 & 1) * 4;
            Sv[ch * 512 + (b0 + 0) * 64 + rg] = q.x;
            Sv[ch * 512 + (b0 + 1) * 64 + rg] = q.y;
            Sv[ch * 512 + (b0 + 2) * 64 + rg] = q.z;
            Sv[ch * 512 + (b0 + 3) * 64 + rg] = q.w;
        }
    }
    __syncthreads();

    int ch = threadIdx.x >> 6;
    int rg = threadIdx.x & 63;
    int r = rg >> 3, g = rg & 7;

    auto SV = [&](int b, int l) -> float { return Sv[ch * 512 + b * 64 + l]; };
    auto gsp = [&](int ccy, int ccx, int rr, int gg, int bb) -> float {
        if (ccy < 2 || ccy > 66 || ccx < 2 || ccx > 66) return 0.0f;
        return src[(long)ch * kT3 + (((long)(ccy * kSW + ccx)) << 9) + (rr << 6) + (gg << 3) + bb];
    };

    bool gI = (g >= 1) && (g <= dg - 2);
    bool rI = (r >= 1) && (r <= dr - 2);

    float v[8];
    #pragma unroll
    for (int b = 0; b < 8; ++b) v[b] = SV(b, rg);

    int eHi = db - 1;

    // iter-1 end values (b = 0 and b = db-1)
    auto o1_end = [&](int e) -> float {
        float Vm, Vp;
        if (gI)      { Vm = SV(e, rg - 1); Vp = SV(e, rg + 1); }
        else if (rI) { Vm = SV(e, rg - 8); Vp = SV(e, rg + 8); }
        else         { Vm = gsp(cy, cx - 1, r, g, e); Vp = gsp(cy, cx + 1, r, g, e); }
        // center term: v at e — dynamic index into LDS, not the private array
        return (Vm + Vp + 2.0f * SV(e, rg)) * 0.25f;
    };
    float o1_lo = o1_end(0);
    float o1_hi = o1_end(eHi);

    float o1[8];
    #pragma unroll
    for (int b = 0; b < 8; ++b) {
        float iv = 0.0f;
        if (b >= 1 && b <= 6) iv = ((v[b - 1] + v[b + 1]) + 2.0f * v[b]) * 0.25f;
        o1[b] = (b >= 1 && b <= db - 2) ? iv : (b == 0 ? o1_lo : (b == eHi ? o1_hi : 0.0f));
    }

    // iter-1 value at a b-end cell of an in-cell neighbor line (r2,g2)
    auto out1_in = [&](int r2, int g2, int e) -> float {
        int l2 = (r2 << 3) + g2;
        float C = SV(e, l2);
        float Nm, Np;
        if (g2 >= 1 && g2 <= dg - 2)      { Nm = SV(e, l2 - 1); Np = SV(e, l2 + 1); }
        else if (r2 >= 1 && r2 <= dr - 2) { Nm = SV(e, l2 - 8); Np = SV(e, l2 + 8); }
        else { Nm = gsp(cy, cx - 1, r2, g2, e); Np = gsp(cy, cx + 1, r2, g2, e); }
        return (Nm + Np + 2.0f * C) * 0.25f;
    };
    // iter-1 value at a b-end cell of the x-neighbor cell line (cx2, same r,g);
    // only called when r,g are both ends -> that line's axis is x (or y at
    // cx2==67, where everything is zero).
    auto out1_x = [&](int cx2, int e) -> float {
        float C = gsp(cy, cx2, r, g, e);
        float Nm, Np;
        if (cx2 >= 1 && cx2 <= kSW - 2) { Nm = gsp(cy, cx2 - 1, r, g, e); Np = gsp(cy, cx2 + 1, r, g, e); }
        else                            { Nm = gsp(cy - 1, cx2, r, g, e); Np = gsp(cy + 1, cx2, r, g, e); }
        return (Nm + Np + 2.0f * C) * 0.25f;
    };

    auto o2_end = [&](int e, float o1e) -> float {
        float Xm, Xp;
        if (gI)      { Xm = out1_in(r, g - 1, e); Xp = out1_in(r, g + 1, e); }
        else if (rI) { Xm = out1_in(r - 1, g, e); Xp = out1_in(r + 1, g, e); }
        else         { Xm = out1_x(cx - 1, e);    Xp = out1_x(cx + 1, e); }
        return (Xm + Xp + 2.0f * o1e) * 0.25f;
    };
    float o2_lo = o2_end(0, o1_lo);
    float o2_hi = o2_end(eHi, o1_hi);

    float o2[8];
    #pragma unroll
    for (int b = 0; b < 8; ++b) {
        float iv = 0.0f;
        if (b >= 1 && b <= 6) iv = ((o1[b - 1] + o1[b + 1]) + 2.0f * o1[b]) * 0.25f;
        o2[b] = (b >= 1 && b <= db - 2) ? iv : (b == 0 ? o2_lo : (b == eHi ? o2_hi : 0.0f));
    }

    __syncthreads();     // done reading Sv; reuse it for the output transpose
    #pragma unroll
    for (int b = 0; b < 8; ++b) Sv[ch * 512 + b * 64 + rg] = o2[b];
    __syncthreads();

    {
        float4* d4 = (float4*)dst;
        for (int i = threadIdx.x; i < 384; i += 192) {
            int c2 = i >> 7, i4 = i & 127;
            int l2 = i4 >> 1;
            int b0 = (i4 & 1) * 4;
            float4 q = make_float4(Sv[c2 * 512 + (b0 + 0) * 64 + l2],
                                   Sv[c2 * 512 + (b0 + 1) * 64 + l2],
                                   Sv[c2 * 512 + (b0 + 2) * 64 + l2],
                                   Sv[c2 * 512 + (b0 + 3) * 64 + l2]);
            d4[(long)c2 * (kT3 / 4) + (cbase >> 2) + i4] = q;
        }
    }
}

// LDS-staged slice: one workgroup per 16x16 pixel tile (known-good R4 config).
__global__ __launch_bounds__(256) void slice_kernel(const float* __restrict__ feat,
                                                    const float* __restrict__ hdrF,
                                                    const float* __restrict__ grid,
                                                    float* __restrict__ out) {
    __shared__ float sg[3 * 4 * 512];   // [ch][cell][512]
    int tx = blockIdx.x, ty = blockIdx.y;   // 64 x 64 tiles

    {
        const float4* g4 = (const float4*)grid;
        float4* s4 = (float4*)sg;
        #pragma unroll
        for (int it = 0; it < 2; ++it) {
            int i = threadIdx.x + it * 256;       // float4 index within a channel plane [0,512)
            int cell = i >> 7;                    // 0..3 = (dy<<1)|dx
            int ci4 = i & 127;
            int cy = ty + 2 + (cell >> 1), cx = tx + 2 + (cell & 1);
            long cbase4 = ((long)(cy * kSW + cx)) << 7;   // 128 float4 per cell
            #pragma unroll
            for (int ch = 0; ch < 3; ++ch)
                s4[ch * 512 + i] = g4[(long)ch * (kT3 / 4) + cbase4 + ci4];
        }
    }
    __syncthreads();

    const int* ip = (const int*)(hdrF + 8);
    int d3[3] = {ip[0], ip[1], ip[2]};
    int lx = threadIdx.x & 15, ly = threadIdx.x >> 4;
    int y = (ty << 4) + ly, x = (tx << 4) + lx;
    int p = (y << 10) + x;

    float ya = (float)ly * 0.0625f;   // exact fractional part of y/16
    float xa = (float)lx * 0.0625f;

    int li[3], ri[3];
    float al[3];
    #pragma unroll
    for (int c = 0; c < 3; ++c) {
        float v0 = feat[p * 3 + c] - hdrF[c];
        float sv = v0 * 4.0f + 2.0f;
        int l = (int)sv;
        int dm = d3[c] - 1;
        l = l < 0 ? 0 : (l > dm ? dm : l);
        int rr = l + 1 > dm ? dm : l + 1;
        li[c] = l; ri[c] = rr; al[c] = sv - (float)l;
    }

    float spw[4];
    {
        float wy[2] = {1.0f - ya, ya};
        float wx[2] = {1.0f - xa, xa};
        spw[0] = wy[0] * wx[0]; spw[1] = wy[0] * wx[1];
        spw[2] = wy[1] * wx[0]; spw[3] = wy[1] * wx[1];
    }
    int cpi[8]; float cpw[8];
    {
        int rs[2] = {li[0], ri[0]}; float wrr[2] = {1.0f - al[0], al[0]};
        int gs[2] = {li[1], ri[1]}; float wgg[2] = {1.0f - al[1], al[1]};
        int bs[2] = {li[2], ri[2]}; float wbb[2] = {1.0f - al[2], al[2]};
        #pragma unroll
        for (int cr = 0; cr < 2; ++cr)
        #pragma unroll
        for (int cg = 0; cg < 2; ++cg)
        #pragma unroll
        for (int cb = 0; cb < 2; ++cb) {
            int k = (cr * 2 + cg) * 2 + cb;
            cpi[k] = (rs[cr] << 6) + (gs[cg] << 3) + bs[cb];
            cpw[k] = (wrr[cr] * wgg[cg]) * wbb[cb];
        }
    }

    float acc0 = 0.0f, acc1 = 0.0f, acc2 = 0.0f;
    #pragma unroll
    for (int k = 0; k < 4; ++k) {
        #pragma unroll
        for (int j = 0; j < 8; ++j) {
            int si = (k << 9) + cpi[j];
            float w = spw[k] * cpw[j];
            acc0 += w * sg[si];
            acc1 += w * sg[2048 + si];
            acc2 += w * sg[4096 + si];
        }
    }
    out[p * 3 + 0] = acc0;
    out[p * 3 + 1] = acc1;
    out[p * 3 + 2] = acc2;
}

}  // namespace

extern "C" void kernel_launch(void* const* d_in, const int* in_sizes, int n_in,
                              void* d_out, int out_size, void* d_ws, size_t ws_size,
                              hipStream_t stream) {
    const float* feat = (const float*)d_in[0];
    const float* inp  = (const float*)d_in[1];
    float* out = (float*)d_out;

    float* hdrF  = (float*)d_ws;
    float* part  = (float*)((char*)d_ws + 1024);       // 256 x 6 floats
    float* gridA = (float*)((char*)d_ws + 8192);       // splat
    float* gridB = gridA + 3 * (size_t)kT3;            // blurred (slice source)

    minmax_kernel<<<256, 256, 0, stream>>>(feat, part);
    params_kernel<<<1, 256, 0, stream>>>(part, hdrF);

    splat_kernel<<<dim3(65, 65), 256, 0, stream>>>(feat, inp, hdrF, gridA);
    blur2_kernel<<<dim3(65, 65), 192, 0, stream>>>(gridB, gridA, hdrF);
    slice_kernel<<<dim3(64, 64), 256, 0, stream>>>(feat, hdrF, gridB, out);
}